// Round 2
// baseline (1334.966 us; speedup 1.0000x reference)
//
#include <hip/hip_runtime.h>
#include <hip/hip_bf16.h>

typedef unsigned short u16;
typedef __attribute__((ext_vector_type(8))) unsigned short u16x8;
typedef __attribute__((ext_vector_type(8))) short bf16x8;
typedef __attribute__((ext_vector_type(4))) float f32x4;

__device__ __forceinline__ u16 f2bs(float f) {
    union { float f; unsigned int u; } x; x.f = f;
    unsigned int r = x.u + 0x7FFFu + ((x.u >> 16) & 1u);   // RNE
    return (u16)(r >> 16);
}
__device__ __forceinline__ float bs2f(u16 u) {
    union { unsigned int u; float f; } x; x.u = ((unsigned int)u) << 16; return x.f;
}
__device__ __forceinline__ float lrelu(float e) { return e >= 0.f ? e : 0.2f * e; }

// ---------------- CSR build ----------------
__global__ void deg_kernel(const int* __restrict__ dst, int* __restrict__ deg, int E) {
    int i = blockIdx.x * 256 + threadIdx.x;
    if (i < E) atomicAdd(&deg[dst[i]], 1);
}

__global__ __launch_bounds__(1024) void scan_kernel(const int* __restrict__ deg,
        int* __restrict__ ptr, int* __restrict__ cur, int N) {
    __shared__ int lds[1024];
    const int t = threadIdx.x;
    int carry = 0;
    if (t == 0) ptr[0] = 0;
    for (int base = 0; base < N; base += 1024) {
        int i = base + t;
        int v = (i < N) ? deg[i] : 0;
        lds[t] = v;
        __syncthreads();
        for (int off = 1; off < 1024; off <<= 1) {
            int add = (t >= off) ? lds[t - off] : 0;
            __syncthreads();
            lds[t] += add;
            __syncthreads();
        }
        int incl = lds[t];
        if (i < N) { ptr[i + 1] = carry + incl; cur[i] = carry + incl - v; }
        carry += lds[1023];
        __syncthreads();
    }
}

__global__ void fill_kernel(const int* __restrict__ src, const int* __restrict__ dst,
        int* __restrict__ cur, int* __restrict__ csr, int E) {
    int i = blockIdx.x * 256 + threadIdx.x;
    if (i < E) { int p = atomicAdd(&cur[dst[i]], 1); csr[p] = src[i]; }
}

// ---------------- weight transpose: fp32 W[K][Nn] -> bf16 Wt[Nn][KT] (zero-pad k>=K) ----
__global__ void transpose_w(const float* __restrict__ W, u16* __restrict__ Wt,
        int K, int Nn, int KT) {
    int idx = blockIdx.x * 256 + threadIdx.x;
    if (idx >= Nn * KT) return;
    int n = idx / KT, k = idx - n * KT;
    Wt[(size_t)n * KT + k] = (k < K) ? f2bs(W[(size_t)k * Nn + n]) : (u16)0;
}

// ---------------- GEMM: C[M,256] fp32 = A[M,K] @ Wt^T (bf16 MFMA) ----------------
// AFP32: A is fp32, converted to bf16 during staging (guarded scalar loads).
// else:  A is bf16 (u16), 16B vector loads (rows must be 16B aligned).
template<bool AFP32>
__global__ __launch_bounds__(256) void gemm128(
        const void* __restrict__ Av, int lda, int M, int K,
        const u16* __restrict__ B, int ldb,
        float* __restrict__ C, int ldc) {
    const float* Af = (const float*)Av;
    const u16*   Au = (const u16*)Av;
    __shared__ u16 Alds[128][40];
    __shared__ u16 Blds[128][40];
    const int t = threadIdx.x;
    const int row0 = blockIdx.x * 128, col0 = blockIdx.y * 128;
    const int wid = t >> 6, lane = t & 63;
    const int wm = wid >> 1, wn = wid & 1;
    const int quad = lane >> 4, l16 = lane & 15;

    f32x4 acc[4][4];
    f32x4 z = {0.f, 0.f, 0.f, 0.f};
    #pragma unroll
    for (int i = 0; i < 4; i++)
        #pragma unroll
        for (int j = 0; j < 4; j++) acc[i][j] = z;

    const int kTiles = (K + 31) >> 5;
    for (int kt = 0; kt < kTiles; ++kt) {
        const int k0 = kt << 5;
        #pragma unroll
        for (int c = 0; c < 2; c++) {
            int ch = t + c * 256;
            int r = ch >> 2, cp = (ch & 3) * 8;
            int gr = row0 + r;
            u16x8 v = {0,0,0,0,0,0,0,0};
            if (AFP32) {
                #pragma unroll
                for (int u = 0; u < 8; u++) {
                    int k = k0 + cp + u;
                    v[u] = (gr < M && k < K) ? f2bs(Af[(size_t)gr * lda + k]) : (u16)0;
                }
            } else {
                if (gr < M) v = *(const u16x8*)(Au + (size_t)gr * lda + k0 + cp);
            }
            *(u16x8*)&Alds[r][cp] = v;
        }
        #pragma unroll
        for (int c = 0; c < 2; c++) {
            int ch = t + c * 256;
            int r = ch >> 2, cp = (ch & 3) * 8;
            *(u16x8*)&Blds[r][cp] = *(const u16x8*)(B + (size_t)(col0 + r) * ldb + k0 + cp);
        }
        __syncthreads();
        bf16x8 af[4], bfr[4];
        #pragma unroll
        for (int it = 0; it < 4; it++) af[it] = *(const bf16x8*)&Alds[wm * 64 + it * 16 + l16][quad * 8];
        #pragma unroll
        for (int jt = 0; jt < 4; jt++) bfr[jt] = *(const bf16x8*)&Blds[wn * 64 + jt * 16 + l16][quad * 8];
        #pragma unroll
        for (int it = 0; it < 4; it++)
            #pragma unroll
            for (int jt = 0; jt < 4; jt++)
                acc[it][jt] = __builtin_amdgcn_mfma_f32_16x16x32_bf16(af[it], bfr[jt], acc[it][jt], 0, 0, 0);
        __syncthreads();
    }
    #pragma unroll
    for (int it = 0; it < 4; it++) {
        int gr0 = row0 + wm * 64 + it * 16 + quad * 4;
        #pragma unroll
        for (int jt = 0; jt < 4; jt++) {
            int gc = col0 + wn * 64 + jt * 16 + l16;
            #pragma unroll
            for (int r = 0; r < 4; r++) {
                int gr = gr0 + r;
                if (gr < M) C[(size_t)gr * ldc + gc] = acc[it][jt][r];
            }
        }
    }
}

// GEMM for layer3: C[M,32] fp32 = A[M,256]bf16 @ Wt3^T
__global__ __launch_bounds__(256) void gemm32(
        const u16* __restrict__ A, int lda, int M, int K,
        const u16* __restrict__ B, int ldb, float* __restrict__ C) {
    __shared__ u16 Alds[128][40];
    __shared__ u16 Blds[32][40];
    const int t = threadIdx.x;
    const int row0 = blockIdx.x * 128;
    const int wid = t >> 6, lane = t & 63;
    const int quad = lane >> 4, l16 = lane & 15;
    f32x4 acc[2][2];
    f32x4 z = {0.f, 0.f, 0.f, 0.f};
    acc[0][0] = z; acc[0][1] = z; acc[1][0] = z; acc[1][1] = z;
    const int kTiles = K >> 5;
    for (int kt = 0; kt < kTiles; ++kt) {
        const int k0 = kt << 5;
        #pragma unroll
        for (int c = 0; c < 2; c++) {
            int ch = t + c * 256;
            int r = ch >> 2, cp = (ch & 3) * 8;
            int gr = row0 + r;
            u16x8 v = {0,0,0,0,0,0,0,0};
            if (gr < M) v = *(const u16x8*)(A + (size_t)gr * lda + k0 + cp);
            *(u16x8*)&Alds[r][cp] = v;
        }
        if (t < 128) {
            int r = t >> 2, cp = (t & 3) * 8;
            *(u16x8*)&Blds[r][cp] = *(const u16x8*)(B + (size_t)r * ldb + k0 + cp);
        }
        __syncthreads();
        bf16x8 af[2], bfr[2];
        #pragma unroll
        for (int it = 0; it < 2; it++) af[it] = *(const bf16x8*)&Alds[wid * 32 + it * 16 + l16][quad * 8];
        #pragma unroll
        for (int jt = 0; jt < 2; jt++) bfr[jt] = *(const bf16x8*)&Blds[jt * 16 + l16][quad * 8];
        #pragma unroll
        for (int it = 0; it < 2; it++)
            #pragma unroll
            for (int jt = 0; jt < 2; jt++)
                acc[it][jt] = __builtin_amdgcn_mfma_f32_16x16x32_bf16(af[it], bfr[jt], acc[it][jt], 0, 0, 0);
        __syncthreads();
    }
    #pragma unroll
    for (int it = 0; it < 2; it++) {
        int gr0 = row0 + wid * 32 + it * 16 + quad * 4;
        #pragma unroll
        for (int jt = 0; jt < 2; jt++) {
            int gc = jt * 16 + l16;
            #pragma unroll
            for (int r = 0; r < 4; r++) {
                int gr = gr0 + r;
                if (gr < M) C[(size_t)gr * 32 + gc] = acc[it][jt][r];
            }
        }
    }
}

// ---------------- attention scalars (H=4, C=64) ----------------
__global__ __launch_bounds__(256) void al_kernel(const float* __restrict__ h,
        const float* __restrict__ a_s, const float* __restrict__ a_d,
        float* __restrict__ als, float* __restrict__ ald, int N) {
    int t = threadIdx.x;
    float as = a_s[t], ad = a_d[t];
    int base = blockIdx.x * 8;
    for (int u = 0; u < 8; u++) {
        int n = base + u;
        if (n >= N) return;
        float hv = h[(size_t)n * 256 + t];
        float ps = hv * as, pd = hv * ad;
        for (int off = 32; off >= 1; off >>= 1) { ps += __shfl_down(ps, off); pd += __shfl_down(pd, off); }
        if ((t & 63) == 0) { int w = t >> 6; als[n * 4 + w] = ps; ald[n * 4 + w] = pd; }
    }
}

__global__ __launch_bounds__(256) void al3_kernel(const float* __restrict__ h3,
        const float* __restrict__ a_s, const float* __restrict__ a_d,
        float* __restrict__ als, float* __restrict__ ald, int N) {
    int t = threadIdx.x, wid = t >> 6, lane = t & 63;
    int c = lane & 31, half = lane >> 5;
    float as = a_s[c], ad = a_d[c];
    int n = blockIdx.x * 8 + wid * 2 + half;
    if (n >= N) return;
    float hv = h3[(size_t)n * 32 + c];
    float ps = hv * as, pd = hv * ad;
    for (int off = 16; off >= 1; off >>= 1) { ps += __shfl_down(ps, off, 32); pd += __shfl_down(pd, off, 32); }
    if (c == 0) { als[n] = ps; ald[n] = pd; }
}

// ---------------- softmax-aggregation (H=4, C=64) -> bf16 act, fused +bias,ReLU ----
__global__ __launch_bounds__(256) void agg_kernel(const float* __restrict__ hbuf,
        const float* __restrict__ als, const float* __restrict__ ald,
        const int* __restrict__ ptr, const int* __restrict__ csr,
        const float* __restrict__ bias, u16* __restrict__ act) {
    const int i = blockIdx.x, t = threadIdx.x;
    const int wid = t >> 6, lane = t & 63;
    const int start = ptr[i], end = ptr[i + 1];
    float aldv[4], eself[4], mx[4];
    #pragma unroll
    for (int hh = 0; hh < 4; hh++) {
        aldv[hh] = ald[i * 4 + hh];
        eself[hh] = lrelu(als[i * 4 + hh] + aldv[hh]);
        mx[hh] = eself[hh];
    }
    for (int j = start + t; j < end; j += 256) {
        int s = csr[j];
        #pragma unroll
        for (int hh = 0; hh < 4; hh++)
            mx[hh] = fmaxf(mx[hh], lrelu(als[s * 4 + hh] + aldv[hh]));
    }
    __shared__ float red[4][4];
    #pragma unroll
    for (int hh = 0; hh < 4; hh++)
        for (int off = 32; off >= 1; off >>= 1) mx[hh] = fmaxf(mx[hh], __shfl_down(mx[hh], off));
    if (lane == 0) { for (int hh = 0; hh < 4; hh++) red[wid][hh] = mx[hh]; }
    __syncthreads();
    float m[4];
    #pragma unroll
    for (int hh = 0; hh < 4; hh++)
        m[hh] = fmaxf(fmaxf(red[0][hh], red[1][hh]), fmaxf(red[2][hh], red[3][hh]));
    __syncthreads();
    float sm[4];
    #pragma unroll
    for (int hh = 0; hh < 4; hh++) sm[hh] = (t == 0) ? expf(eself[hh] - m[hh]) : 0.f;
    for (int j = start + t; j < end; j += 256) {
        int s = csr[j];
        #pragma unroll
        for (int hh = 0; hh < 4; hh++)
            sm[hh] += expf(lrelu(als[s * 4 + hh] + aldv[hh]) - m[hh]);
    }
    #pragma unroll
    for (int hh = 0; hh < 4; hh++)
        for (int off = 32; off >= 1; off >>= 1) sm[hh] += __shfl_down(sm[hh], off);
    if (lane == 0) { for (int hh = 0; hh < 4; hh++) red[wid][hh] = sm[hh]; }
    __syncthreads();
    float inv[4];
    #pragma unroll
    for (int hh = 0; hh < 4; hh++)
        inv[hh] = 1.f / (red[0][hh] + red[1][hh] + red[2][hh] + red[3][hh] + 1e-16f);

    const int hh = t >> 6;
    const float mh = m[hh], invh = inv[hh], aldh = aldv[hh];
    float acc = expf(eself[hh] - mh) * invh * hbuf[(size_t)i * 256 + t];
    for (int j = start; j < end; j++) {
        int s = csr[j];
        float alpha = expf(lrelu(als[s * 4 + hh] + aldh) - mh) * invh;
        acc += alpha * hbuf[(size_t)s * 256 + t];
    }
    float val = fmaxf(acc + bias[t], 0.f);                 // + b, ReLU
    act[(size_t)i * 256 + t] = f2bs(val);
}

// ---------------- layer-3 aggregation (H=1, C=32) fused with mean-pool ----------------
__global__ __launch_bounds__(64) void agg3_kernel(const float* __restrict__ h3,
        const float* __restrict__ als, const float* __restrict__ ald,
        const int* __restrict__ ptr, const int* __restrict__ csr,
        const float* __restrict__ bias, const int* __restrict__ batch,
        float* __restrict__ pool, int* __restrict__ cnt) {
    const int i = blockIdx.x, lane = threadIdx.x;
    const int start = ptr[i], end = ptr[i + 1];
    const float aldv = ald[i];
    float e0 = lrelu(als[i] + aldv);
    float mx = e0;
    for (int j = start + lane; j < end; j += 64) {
        int s = csr[j]; mx = fmaxf(mx, lrelu(als[s] + aldv));
    }
    for (int off = 32; off >= 1; off >>= 1) mx = fmaxf(mx, __shfl_down(mx, off));
    float m = __shfl(mx, 0);
    float sm = (lane == 0) ? expf(e0 - m) : 0.f;
    for (int j = start + lane; j < end; j += 64) {
        int s = csr[j]; sm += expf(lrelu(als[s] + aldv) - m);
    }
    for (int off = 32; off >= 1; off >>= 1) sm += __shfl_down(sm, off);
    float inv = 1.f / (__shfl(sm, 0) + 1e-16f);
    int c = lane & 31, half = lane >> 5;
    float acc = (half == 0) ? expf(e0 - m) * inv * h3[(size_t)i * 32 + c] : 0.f;
    for (int j = start + half; j < end; j += 2) {
        int s = csr[j];
        float alpha = expf(lrelu(als[s] + aldv) - m) * inv;
        acc += alpha * h3[(size_t)s * 32 + c];
    }
    acc += __shfl_down(acc, 32);
    if (lane < 32) {
        float val = acc + bias[c];             // no ReLU on layer 3
        int g = batch[i];
        atomicAdd(&pool[g * 32 + c], val);
        if (lane == 0) atomicAdd(&cnt[g], 1);
    }
}

__global__ void final_kernel(const float* __restrict__ pool, const int* __restrict__ cnt,
        float* __restrict__ out) {
    int idx = blockIdx.x * 256 + threadIdx.x;
    int g = idx >> 5;
    out[idx] = pool[idx] / fmaxf((float)cnt[g], 1.f);
}

extern "C" void kernel_launch(void* const* d_in, const int* in_sizes, int n_in,
                              void* d_out, int out_size, void* d_ws, size_t ws_size,
                              hipStream_t stream) {
    const int N = 50000, E = 800000, G = 512;
    const float* x    = (const float*)d_in[0];
    const int*   ei   = (const int*)d_in[1];
    const int*   batch= (const int*)d_in[2];
    const float* W1   = (const float*)d_in[3];
    const float* as1  = (const float*)d_in[4];
    const float* ad1  = (const float*)d_in[5];
    const float* b1   = (const float*)d_in[6];
    const float* W2   = (const float*)d_in[7];
    const float* as2  = (const float*)d_in[8];
    const float* ad2  = (const float*)d_in[9];
    const float* b2   = (const float*)d_in[10];
    const float* W3   = (const float*)d_in[11];
    const float* as3  = (const float*)d_in[12];
    const float* ad3  = (const float*)d_in[13];
    const float* b3   = (const float*)d_in[14];
    const int* esrc = ei;
    const int* edst = ei + E;

    char* base = (char*)d_ws; size_t off = 0;
    auto alloc = [&](size_t bytes) -> void* {
        void* p = base + off; off = (off + bytes + 255) & ~(size_t)255; return p;
    };
    float* hbuf = (float*)alloc((size_t)N * 256 * 4);   // GEMM out / messages (fp32)
    u16*   act  = (u16*)  alloc((size_t)N * 256 * 2);   // bf16 activations
    float* als  = (float*)alloc((size_t)N * 4 * 4);
    float* ald  = (float*)alloc((size_t)N * 4 * 4);
    int*   deg  = (int*)  alloc((size_t)N * 4);
    int*   ptr  = (int*)  alloc((size_t)(N + 1) * 4);
    int*   cur  = (int*)  alloc((size_t)N * 4);
    int*   csr  = (int*)  alloc((size_t)E * 4);
    u16*   Wt   = (u16*)  alloc((size_t)256 * 800 * 2);
    float* pool = (float*)alloc((size_t)G * 32 * 4);
    int*   cnt  = (int*)  alloc((size_t)G * 4);

    hipMemsetAsync(deg, 0, (size_t)N * 4, stream);
    hipMemsetAsync(pool, 0, (size_t)G * 32 * 4, stream);
    hipMemsetAsync(cnt, 0, (size_t)G * 4, stream);

    // CSR over dst (reused by all 3 layers; self-loops handled via eself term)
    deg_kernel<<<(E + 255) / 256, 256, 0, stream>>>(edst, deg, E);
    scan_kernel<<<1, 1024, 0, stream>>>(deg, ptr, cur, N);
    fill_kernel<<<(E + 255) / 256, 256, 0, stream>>>(esrc, edst, cur, csr, E);

    dim3 g128((N + 127) / 128, 2);
    // ---- layer 1 ----
    transpose_w<<<(256 * 800 + 255) / 256, 256, 0, stream>>>(W1, Wt, 775, 256, 800);
    gemm128<true><<<g128, 256, 0, stream>>>(x, 775, N, 775, Wt, 800, hbuf, 256);
    al_kernel<<<(N + 7) / 8, 256, 0, stream>>>(hbuf, as1, ad1, als, ald, N);
    agg_kernel<<<N, 256, 0, stream>>>(hbuf, als, ald, ptr, csr, b1, act);
    // ---- layer 2 ----
    transpose_w<<<(256 * 256 + 255) / 256, 256, 0, stream>>>(W2, Wt, 256, 256, 256);
    gemm128<false><<<g128, 256, 0, stream>>>(act, 256, N, 256, Wt, 256, hbuf, 256);
    al_kernel<<<(N + 7) / 8, 256, 0, stream>>>(hbuf, as2, ad2, als, ald, N);
    agg_kernel<<<N, 256, 0, stream>>>(hbuf, als, ald, ptr, csr, b2, act);
    // ---- layer 3 ----
    transpose_w<<<(32 * 256 + 255) / 256, 256, 0, stream>>>(W3, Wt, 256, 32, 256);
    gemm32<<<(N + 127) / 128, 256, 0, stream>>>(act, 256, N, 256, Wt, 256, hbuf);
    al3_kernel<<<(N + 7) / 8, 256, 0, stream>>>(hbuf, as3, ad3, als, ald, N);
    agg3_kernel<<<N, 64, 0, stream>>>(hbuf, als, ald, ptr, csr, b3, batch, pool, cnt);
    final_kernel<<<(G * 32 + 255) / 256, 256, 0, stream>>>(pool, cnt, (float*)d_out);
}

// Round 3
// 963.194 us; speedup vs baseline: 1.3860x; 1.3860x over previous
//
#include <hip/hip_runtime.h>
#include <hip/hip_bf16.h>

typedef unsigned short u16;
typedef __attribute__((ext_vector_type(8))) unsigned short u16x8;
typedef __attribute__((ext_vector_type(8))) short bf16x8;
typedef __attribute__((ext_vector_type(4))) float f32x4;

__device__ __forceinline__ u16 f2bs(float f) {
    union { float f; unsigned int u; } x; x.f = f;
    unsigned int r = x.u + 0x7FFFu + ((x.u >> 16) & 1u);   // RNE
    return (u16)(r >> 16);
}
__device__ __forceinline__ float lrelu(float e) { return e >= 0.f ? e : 0.2f * e; }

// ---------------- CSR build ----------------
__global__ void deg_kernel(const int* __restrict__ dst, int* __restrict__ deg, int E) {
    int i = blockIdx.x * 256 + threadIdx.x;
    if (i < E) atomicAdd(&deg[dst[i]], 1);
}

// hierarchical scan: local (1024/block) -> carry scan -> fixup
__global__ __launch_bounds__(1024) void scan_local(const int* __restrict__ deg,
        int* __restrict__ ptr, int* __restrict__ bsum, int N) {
    __shared__ int wsum[16];
    const int t = threadIdx.x, i = blockIdx.x * 1024 + t;
    const int lane = t & 63, w = t >> 6;
    int v = (i < N) ? deg[i] : 0;
    int x = v;
    #pragma unroll
    for (int off = 1; off < 64; off <<= 1) { int y = __shfl_up(x, off); if (lane >= off) x += y; }
    if (lane == 63) wsum[w] = x;
    __syncthreads();
    if (w == 0) {
        int s = (lane < 16) ? wsum[lane] : 0;
        #pragma unroll
        for (int off = 1; off < 16; off <<= 1) { int y = __shfl_up(s, off); if (lane >= off) s += y; }
        if (lane < 16) wsum[lane] = s;
    }
    __syncthreads();
    int incl = x + (w > 0 ? wsum[w - 1] : 0);
    if (i < N) ptr[i + 1] = incl;            // local inclusive; fixed by scan_final
    if (t == 0) bsum[blockIdx.x] = wsum[15];
}

__global__ __launch_bounds__(64) void scan_carry(int* __restrict__ bsum, int nb) {
    int t = threadIdx.x;
    int v = (t < nb) ? bsum[t] : 0;
    int x = v;
    #pragma unroll
    for (int off = 1; off < 64; off <<= 1) { int y = __shfl_up(x, off); if (t >= off) x += y; }
    if (t < nb) bsum[t] = x - v;             // exclusive
}

__global__ __launch_bounds__(1024) void scan_final(const int* __restrict__ deg,
        int* __restrict__ ptr, int* __restrict__ cur, const int* __restrict__ bsum, int N) {
    int i = blockIdx.x * 1024 + threadIdx.x;
    if (i == 0) ptr[0] = 0;
    if (i < N) {
        int p = ptr[i + 1] + bsum[blockIdx.x];
        ptr[i + 1] = p;
        cur[i] = p - deg[i];
    }
}

__global__ void fill_kernel(const int* __restrict__ src, const int* __restrict__ dst,
        int* __restrict__ cur, int* __restrict__ csr, int E) {
    int i = blockIdx.x * 256 + threadIdx.x;
    if (i < E) { int p = atomicAdd(&cur[dst[i]], 1); csr[p] = src[i]; }
}

// ---------------- weight transpose: fp32 W[K][Nn] -> bf16 Wt[Nn][KT] (zero-pad k>=K) ----
__global__ void transpose_w(const float* __restrict__ W, u16* __restrict__ Wt,
        int K, int Nn, int KT) {
    int idx = blockIdx.x * 256 + threadIdx.x;
    if (idx >= Nn * KT) return;
    int n = idx / KT, k = idx - n * KT;
    Wt[(size_t)n * KT + k] = (k < K) ? f2bs(W[(size_t)k * Nn + n]) : (u16)0;
}

// ---------------- x fp32[775] -> bf16[800] padded ----------------
__global__ __launch_bounds__(256) void conv_x(const float* __restrict__ x, u16* __restrict__ xbf) {
    int r = blockIdx.x, t = threadIdx.x;
    const float* row = x + (size_t)r * 775;
    u16* orow = xbf + (size_t)r * 800;
    for (int k = t; k < 800; k += 256)
        orow[k] = (k < 775) ? f2bs(row[k]) : (u16)0;
}

// ---------------- GEMM: C[M,256] fp32 = A[M,K] @ Wt^T (bf16 MFMA) ----------------
template<bool AFP32>
__global__ __launch_bounds__(256) void gemm128(
        const void* __restrict__ Av, int lda, int M, int K,
        const u16* __restrict__ B, int ldb,
        float* __restrict__ C, int ldc) {
    const float* Af = (const float*)Av;
    const u16*   Au = (const u16*)Av;
    __shared__ u16 Alds[128][40];
    __shared__ u16 Blds[128][40];
    const int t = threadIdx.x;
    const int row0 = blockIdx.x * 128, col0 = blockIdx.y * 128;
    const int wid = t >> 6, lane = t & 63;
    const int wm = wid >> 1, wn = wid & 1;
    const int quad = lane >> 4, l16 = lane & 15;

    f32x4 acc[4][4];
    f32x4 z = {0.f, 0.f, 0.f, 0.f};
    #pragma unroll
    for (int i = 0; i < 4; i++)
        #pragma unroll
        for (int j = 0; j < 4; j++) acc[i][j] = z;

    const int kTiles = (K + 31) >> 5;
    for (int kt = 0; kt < kTiles; ++kt) {
        const int k0 = kt << 5;
        #pragma unroll
        for (int c = 0; c < 2; c++) {
            int ch = t + c * 256;
            int r = ch >> 2, cp = (ch & 3) * 8;
            int gr = row0 + r;
            u16x8 v = {0,0,0,0,0,0,0,0};
            if (AFP32) {
                #pragma unroll
                for (int u = 0; u < 8; u++) {
                    int k = k0 + cp + u;
                    v[u] = (gr < M && k < K) ? f2bs(Af[(size_t)gr * lda + k]) : (u16)0;
                }
            } else {
                if (gr < M) v = *(const u16x8*)(Au + (size_t)gr * lda + k0 + cp);
            }
            *(u16x8*)&Alds[r][cp] = v;
        }
        #pragma unroll
        for (int c = 0; c < 2; c++) {
            int ch = t + c * 256;
            int r = ch >> 2, cp = (ch & 3) * 8;
            *(u16x8*)&Blds[r][cp] = *(const u16x8*)(B + (size_t)(col0 + r) * ldb + k0 + cp);
        }
        __syncthreads();
        bf16x8 af[4], bfr[4];
        #pragma unroll
        for (int it = 0; it < 4; it++) af[it] = *(const bf16x8*)&Alds[wm * 64 + it * 16 + l16][quad * 8];
        #pragma unroll
        for (int jt = 0; jt < 4; jt++) bfr[jt] = *(const bf16x8*)&Blds[wn * 64 + jt * 16 + l16][quad * 8];
        #pragma unroll
        for (int it = 0; it < 4; it++)
            #pragma unroll
            for (int jt = 0; jt < 4; jt++)
                acc[it][jt] = __builtin_amdgcn_mfma_f32_16x16x32_bf16(af[it], bfr[jt], acc[it][jt], 0, 0, 0);
        __syncthreads();
    }
    #pragma unroll
    for (int it = 0; it < 4; it++) {
        int gr0 = row0 + wm * 64 + it * 16 + quad * 4;
        #pragma unroll
        for (int jt = 0; jt < 4; jt++) {
            int gc = col0 + wn * 64 + jt * 16 + l16;
            #pragma unroll
            for (int r = 0; r < 4; r++) {
                int gr = gr0 + r;
                if (gr < M) C[(size_t)gr * ldc + gc] = acc[it][jt][r];
            }
        }
    }
}

// GEMM for layer3: C[M,32] fp32 = A[M,256]bf16 @ Wt3^T
__global__ __launch_bounds__(256) void gemm32(
        const u16* __restrict__ A, int lda, int M, int K,
        const u16* __restrict__ B, int ldb, float* __restrict__ C) {
    __shared__ u16 Alds[128][40];
    __shared__ u16 Blds[32][40];
    const int t = threadIdx.x;
    const int row0 = blockIdx.x * 128;
    const int wid = t >> 6, lane = t & 63;
    const int quad = lane >> 4, l16 = lane & 15;
    f32x4 acc[2][2];
    f32x4 z = {0.f, 0.f, 0.f, 0.f};
    acc[0][0] = z; acc[0][1] = z; acc[1][0] = z; acc[1][1] = z;
    const int kTiles = K >> 5;
    for (int kt = 0; kt < kTiles; ++kt) {
        const int k0 = kt << 5;
        #pragma unroll
        for (int c = 0; c < 2; c++) {
            int ch = t + c * 256;
            int r = ch >> 2, cp = (ch & 3) * 8;
            int gr = row0 + r;
            u16x8 v = {0,0,0,0,0,0,0,0};
            if (gr < M) v = *(const u16x8*)(A + (size_t)gr * lda + k0 + cp);
            *(u16x8*)&Alds[r][cp] = v;
        }
        if (t < 128) {
            int r = t >> 2, cp = (t & 3) * 8;
            *(u16x8*)&Blds[r][cp] = *(const u16x8*)(B + (size_t)r * ldb + k0 + cp);
        }
        __syncthreads();
        bf16x8 af[2], bfr[2];
        #pragma unroll
        for (int it = 0; it < 2; it++) af[it] = *(const bf16x8*)&Alds[wid * 32 + it * 16 + l16][quad * 8];
        #pragma unroll
        for (int jt = 0; jt < 2; jt++) bfr[jt] = *(const bf16x8*)&Blds[jt * 16 + l16][quad * 8];
        #pragma unroll
        for (int it = 0; it < 2; it++)
            #pragma unroll
            for (int jt = 0; jt < 2; jt++)
                acc[it][jt] = __builtin_amdgcn_mfma_f32_16x16x32_bf16(af[it], bfr[jt], acc[it][jt], 0, 0, 0);
        __syncthreads();
    }
    #pragma unroll
    for (int it = 0; it < 2; it++) {
        int gr0 = row0 + wid * 32 + it * 16 + quad * 4;
        #pragma unroll
        for (int jt = 0; jt < 2; jt++) {
            int gc = jt * 16 + l16;
            #pragma unroll
            for (int r = 0; r < 4; r++) {
                int gr = gr0 + r;
                if (gr < M) C[(size_t)gr * 32 + gc] = acc[it][jt][r];
            }
        }
    }
}

// ---------------- attention scalars (H=4, C=64) ----------------
__global__ __launch_bounds__(256) void al_kernel(const float* __restrict__ h,
        const float* __restrict__ a_s, const float* __restrict__ a_d,
        float* __restrict__ als, float* __restrict__ ald, int N) {
    int t = threadIdx.x;
    float as = a_s[t], ad = a_d[t];
    int base = blockIdx.x * 8;
    for (int u = 0; u < 8; u++) {
        int n = base + u;
        if (n >= N) return;
        float hv = h[(size_t)n * 256 + t];
        float ps = hv * as, pd = hv * ad;
        for (int off = 32; off >= 1; off >>= 1) { ps += __shfl_down(ps, off); pd += __shfl_down(pd, off); }
        if ((t & 63) == 0) { int w = t >> 6; als[n * 4 + w] = ps; ald[n * 4 + w] = pd; }
    }
}

__global__ __launch_bounds__(256) void al3_kernel(const float* __restrict__ h3,
        const float* __restrict__ a_s, const float* __restrict__ a_d,
        float* __restrict__ als, float* __restrict__ ald, int N) {
    int t = threadIdx.x, wid = t >> 6, lane = t & 63;
    int c = lane & 31, half = lane >> 5;
    float as = a_s[c], ad = a_d[c];
    int n = blockIdx.x * 8 + wid * 2 + half;
    if (n >= N) return;
    float hv = h3[(size_t)n * 32 + c];
    float ps = hv * as, pd = hv * ad;
    for (int off = 16; off >= 1; off >>= 1) { ps += __shfl_down(ps, off, 32); pd += __shfl_down(pd, off, 32); }
    if (c == 0) { als[n] = ps; ald[n] = pd; }
}

// ---------------- softmax-aggregation (H=4, C=64) -> bf16 act ----------------
// Phase A: edge-parallel e=lrelu(...) -> ews, max-reduce.
// Phase B: edge-parallel exp(e-m) -> ews, sum-reduce.
// Phase C: 4 waves split edges; each wave gathers full 256-ch row float4/lane; LDS reduce.
__global__ __launch_bounds__(256) void agg_kernel(const float* __restrict__ hbuf,
        const float* __restrict__ als, const float* __restrict__ ald,
        const int* __restrict__ ptr, const int* __restrict__ csr,
        float* __restrict__ ews,
        const float* __restrict__ bias, u16* __restrict__ act) {
    const int i = blockIdx.x, t = threadIdx.x;
    const int wid = t >> 6, lane = t & 63;
    const int start = ptr[i], end = ptr[i + 1];
    __shared__ float red[4][4];
    __shared__ float accl[4][64][4];

    const f32x4 aldv = *(const f32x4*)&ald[(size_t)i * 4];
    const f32x4 alsv = *(const f32x4*)&als[(size_t)i * 4];
    float eself[4], mx[4];
    #pragma unroll
    for (int hh = 0; hh < 4; hh++) { eself[hh] = lrelu(alsv[hh] + aldv[hh]); mx[hh] = eself[hh]; }

    for (int j = start + t; j < end; j += 256) {
        int s = csr[j];
        const f32x4 a = *(const f32x4*)&als[(size_t)s * 4];
        f32x4 e;
        #pragma unroll
        for (int hh = 0; hh < 4; hh++) { e[hh] = lrelu(a[hh] + aldv[hh]); mx[hh] = fmaxf(mx[hh], e[hh]); }
        *(f32x4*)&ews[(size_t)j * 4] = e;
    }
    #pragma unroll
    for (int hh = 0; hh < 4; hh++)
        for (int off = 32; off >= 1; off >>= 1) mx[hh] = fmaxf(mx[hh], __shfl_down(mx[hh], off));
    if (lane == 0) {
        #pragma unroll
        for (int hh = 0; hh < 4; hh++) red[wid][hh] = mx[hh];
    }
    __syncthreads();                                  // also drains Phase-A global stores
    float m[4];
    #pragma unroll
    for (int hh = 0; hh < 4; hh++)
        m[hh] = fmaxf(fmaxf(red[0][hh], red[1][hh]), fmaxf(red[2][hh], red[3][hh]));
    __syncthreads();

    float sm[4];
    #pragma unroll
    for (int hh = 0; hh < 4; hh++) sm[hh] = (t == 0) ? expf(eself[hh] - m[hh]) : 0.f;
    for (int j = start + t; j < end; j += 256) {
        f32x4 e = *(const f32x4*)&ews[(size_t)j * 4];
        #pragma unroll
        for (int hh = 0; hh < 4; hh++) { e[hh] = expf(e[hh] - m[hh]); sm[hh] += e[hh]; }
        *(f32x4*)&ews[(size_t)j * 4] = e;
    }
    #pragma unroll
    for (int hh = 0; hh < 4; hh++)
        for (int off = 32; off >= 1; off >>= 1) sm[hh] += __shfl_down(sm[hh], off);
    if (lane == 0) {
        #pragma unroll
        for (int hh = 0; hh < 4; hh++) red[wid][hh] = sm[hh];
    }
    __syncthreads();                                  // also drains Phase-B global stores
    float inv[4];
    #pragma unroll
    for (int hh = 0; hh < 4; hh++)
        inv[hh] = 1.f / (red[0][hh] + red[1][hh] + red[2][hh] + red[3][hh] + 1e-16f);

    // Phase C
    const int head = lane >> 4;                       // head of this lane's 4 channels
    float invsel = head == 0 ? inv[0] : head == 1 ? inv[1] : head == 2 ? inv[2] : inv[3];
    f32x4 acc = {0.f, 0.f, 0.f, 0.f};
    for (int j = start + wid; j < end; j += 4) {
        int s = csr[j];
        float al = ews[(size_t)j * 4 + head] * invsel;
        const f32x4 hv = *(const f32x4*)&hbuf[(size_t)s * 256 + lane * 4];
        #pragma unroll
        for (int c2 = 0; c2 < 4; c2++) acc[c2] = fmaf(al, hv[c2], acc[c2]);
    }
    *(f32x4*)&accl[wid][lane][0] = acc;
    __syncthreads();
    // channel t = accl[w][t>>2][t&3] which is linear element t of each wave's slab
    const float* fl = &accl[0][0][0];
    float v = fl[t] + fl[256 + t] + fl[512 + t] + fl[768 + t];
    int hh2 = t >> 6;
    float msel  = hh2 == 0 ? m[0]  : hh2 == 1 ? m[1]  : hh2 == 2 ? m[2]  : m[3];
    float isel  = hh2 == 0 ? inv[0]: hh2 == 1 ? inv[1]: hh2 == 2 ? inv[2]: inv[3];
    float esel  = hh2 == 0 ? eself[0] : hh2 == 1 ? eself[1] : hh2 == 2 ? eself[2] : eself[3];
    float aself = expf(esel - msel) * isel;
    float val = fmaxf(v + aself * hbuf[(size_t)i * 256 + t] + bias[t], 0.f);
    act[(size_t)i * 256 + t] = f2bs(val);
}

// ---------------- layer-3 aggregation (H=1, C=32) fused with mean-pool ----------------
__global__ __launch_bounds__(64) void agg3_kernel(const float* __restrict__ h3,
        const float* __restrict__ als, const float* __restrict__ ald,
        const int* __restrict__ ptr, const int* __restrict__ csr,
        float* __restrict__ ews,
        const float* __restrict__ bias, const int* __restrict__ batch,
        float* __restrict__ pool, int* __restrict__ cnt) {
    const int i = blockIdx.x, lane = threadIdx.x;
    const int start = ptr[i], end = ptr[i + 1];
    const float aldv = ald[i];
    float e0 = lrelu(als[i] + aldv);
    float mx = e0;
    for (int j = start + lane; j < end; j += 64) {
        int s = csr[j]; mx = fmaxf(mx, lrelu(als[s] + aldv));
    }
    for (int off = 32; off >= 1; off >>= 1) mx = fmaxf(mx, __shfl_down(mx, off));
    float m = __shfl(mx, 0);
    float sm = (lane == 0) ? expf(e0 - m) : 0.f;
    for (int j = start + lane; j < end; j += 64) {
        int s = csr[j];
        float ex = expf(lrelu(als[s] + aldv) - m);
        ews[j] = ex;
        sm += ex;
    }
    for (int off = 32; off >= 1; off >>= 1) sm += __shfl_down(sm, off);
    float inv = 1.f / (__shfl(sm, 0) + 1e-16f);
    __syncthreads();                                  // drain ews stores
    int c = lane & 31, half = lane >> 5;
    float acc = 0.f;
    for (int j = start + half; j < end; j += 2) {
        int s = csr[j];
        acc = fmaf(ews[j] * inv, h3[(size_t)s * 32 + c], acc);
    }
    acc += __shfl_down(acc, 32);
    if (lane < 32) {
        float val = acc + expf(e0 - m) * inv * h3[(size_t)i * 32 + c] + bias[c];
        int g = batch[i];
        atomicAdd(&pool[g * 32 + c], val);
        if (lane == 0) atomicAdd(&cnt[g], 1);
    }
}

__global__ void final_kernel(const float* __restrict__ pool, const int* __restrict__ cnt,
        float* __restrict__ out) {
    int idx = blockIdx.x * 256 + threadIdx.x;
    int g = idx >> 5;
    out[idx] = pool[idx] / fmaxf((float)cnt[g], 1.f);
}

extern "C" void kernel_launch(void* const* d_in, const int* in_sizes, int n_in,
                              void* d_out, int out_size, void* d_ws, size_t ws_size,
                              hipStream_t stream) {
    const int N = 50000, E = 800000, G = 512;
    const float* x    = (const float*)d_in[0];
    const int*   ei   = (const int*)d_in[1];
    const int*   batch= (const int*)d_in[2];
    const float* W1   = (const float*)d_in[3];
    const float* as1  = (const float*)d_in[4];
    const float* ad1  = (const float*)d_in[5];
    const float* b1   = (const float*)d_in[6];
    const float* W2   = (const float*)d_in[7];
    const float* as2  = (const float*)d_in[8];
    const float* ad2  = (const float*)d_in[9];
    const float* b2   = (const float*)d_in[10];
    const float* W3   = (const float*)d_in[11];
    const float* as3  = (const float*)d_in[12];
    const float* ad3  = (const float*)d_in[13];
    const float* b3   = (const float*)d_in[14];
    const int* esrc = ei;
    const int* edst = ei + E;

    char* base = (char*)d_ws; size_t off = 0;
    auto alloc = [&](size_t bytes) -> void* {
        void* p = base + off; off = (off + bytes + 255) & ~(size_t)255; return p;
    };
    float* hbuf = (float*)alloc((size_t)N * 256 * 4);   // GEMM out / messages (fp32)
    u16*   act  = (u16*)  alloc((size_t)N * 256 * 2);   // bf16 activations
    float* ews  = (float*)alloc((size_t)E * 4 * 4);     // per-edge exp workspace
    float* als  = (float*)alloc((size_t)N * 4 * 4);
    float* ald  = (float*)alloc((size_t)N * 4 * 4);
    int*   deg  = (int*)  alloc((size_t)N * 4);
    int*   ptr  = (int*)  alloc((size_t)(N + 1) * 4);
    int*   cur  = (int*)  alloc((size_t)N * 4);
    int*   csr  = (int*)  alloc((size_t)E * 4);
    u16*   Wt   = (u16*)  alloc((size_t)256 * 800 * 2);
    int*   bsum = (int*)  alloc((size_t)64 * 4);
    float* pool = (float*)alloc((size_t)G * 32 * 4);
    int*   cnt  = (int*)  alloc((size_t)G * 4);
    size_t off_mand = off;
    u16*   xbf  = (u16*)  alloc((size_t)N * 800 * 2);   // optional fast path
    const bool use_xbf = (off <= ws_size);              // deterministic per-run

    hipMemsetAsync(deg, 0, (size_t)N * 4, stream);
    hipMemsetAsync(pool, 0, (size_t)G * 32 * 4, stream);
    hipMemsetAsync(cnt, 0, (size_t)G * 4, stream);
    (void)off_mand;

    // CSR over dst (reused by all 3 layers; self-loop handled via eself term)
    const int nb = (N + 1023) / 1024;
    deg_kernel<<<(E + 255) / 256, 256, 0, stream>>>(edst, deg, E);
    scan_local<<<nb, 1024, 0, stream>>>(deg, ptr, bsum, N);
    scan_carry<<<1, 64, 0, stream>>>(bsum, nb);
    scan_final<<<nb, 1024, 0, stream>>>(deg, ptr, cur, bsum, N);
    fill_kernel<<<(E + 255) / 256, 256, 0, stream>>>(esrc, edst, cur, csr, E);

    dim3 g128((N + 127) / 128, 2);
    // ---- layer 1 ----
    transpose_w<<<(256 * 800 + 255) / 256, 256, 0, stream>>>(W1, Wt, 775, 256, 800);
    if (use_xbf) {
        conv_x<<<N, 256, 0, stream>>>(x, xbf);
        gemm128<false><<<g128, 256, 0, stream>>>(xbf, 800, N, 775, Wt, 800, hbuf, 256);
    } else {
        gemm128<true><<<g128, 256, 0, stream>>>(x, 775, N, 775, Wt, 800, hbuf, 256);
    }
    al_kernel<<<(N + 7) / 8, 256, 0, stream>>>(hbuf, as1, ad1, als, ald, N);
    agg_kernel<<<N, 256, 0, stream>>>(hbuf, als, ald, ptr, csr, ews, b1, act);
    // ---- layer 2 ----
    transpose_w<<<(256 * 256 + 255) / 256, 256, 0, stream>>>(W2, Wt, 256, 256, 256);
    gemm128<false><<<g128, 256, 0, stream>>>(act, 256, N, 256, Wt, 256, hbuf, 256);
    al_kernel<<<(N + 7) / 8, 256, 0, stream>>>(hbuf, as2, ad2, als, ald, N);
    agg_kernel<<<N, 256, 0, stream>>>(hbuf, als, ald, ptr, csr, ews, b2, act);
    // ---- layer 3 ----
    transpose_w<<<(32 * 256 + 255) / 256, 256, 0, stream>>>(W3, Wt, 256, 32, 256);
    gemm32<<<(N + 127) / 128, 256, 0, stream>>>(act, 256, N, 256, Wt, 256, hbuf);
    al3_kernel<<<(N + 7) / 8, 256, 0, stream>>>(hbuf, as3, ad3, als, ald, N);
    agg3_kernel<<<N, 64, 0, stream>>>(hbuf, als, ald, ptr, csr, ews, b3, batch, pool, cnt);
    final_kernel<<<(G * 32 + 255) / 256, 256, 0, stream>>>(pool, cnt, (float*)d_out);
}

// Round 4
// 868.183 us; speedup vs baseline: 1.5377x; 1.1094x over previous
//
#include <hip/hip_runtime.h>
#include <hip/hip_bf16.h>

typedef unsigned short u16;
typedef __attribute__((ext_vector_type(4))) unsigned short u16x4;
typedef __attribute__((ext_vector_type(8))) unsigned short u16x8;
typedef __attribute__((ext_vector_type(8))) short bf16x8;
typedef __attribute__((ext_vector_type(4))) float f32x4;

__device__ __forceinline__ u16 f2bs(float f) {
    union { float f; unsigned int u; } x; x.f = f;
    unsigned int r = x.u + 0x7FFFu + ((x.u >> 16) & 1u);   // RNE
    return (u16)(r >> 16);
}
__device__ __forceinline__ float lrelu(float e) { return e >= 0.f ? e : 0.2f * e; }

// ---------------- CSR build ----------------
__global__ void deg_kernel(const int* __restrict__ dst, int* __restrict__ deg, int E) {
    int i = blockIdx.x * 256 + threadIdx.x;
    if (i < E) atomicAdd(&deg[dst[i]], 1);
}

// hierarchical scan: local (1024/block) -> carry scan -> fixup
__global__ __launch_bounds__(1024) void scan_local(const int* __restrict__ deg,
        int* __restrict__ ptr, int* __restrict__ bsum, int N) {
    __shared__ int wsum[16];
    const int t = threadIdx.x, i = blockIdx.x * 1024 + t;
    const int lane = t & 63, w = t >> 6;
    int v = (i < N) ? deg[i] : 0;
    int x = v;
    #pragma unroll
    for (int off = 1; off < 64; off <<= 1) { int y = __shfl_up(x, off); if (lane >= off) x += y; }
    if (lane == 63) wsum[w] = x;
    __syncthreads();
    if (w == 0) {
        int s = (lane < 16) ? wsum[lane] : 0;
        #pragma unroll
        for (int off = 1; off < 16; off <<= 1) { int y = __shfl_up(s, off); if (lane >= off) s += y; }
        if (lane < 16) wsum[lane] = s;
    }
    __syncthreads();
    int incl = x + (w > 0 ? wsum[w - 1] : 0);
    if (i < N) ptr[i + 1] = incl;            // local inclusive; fixed by scan_final
    if (t == 0) bsum[blockIdx.x] = wsum[15];
}

__global__ __launch_bounds__(64) void scan_carry(int* __restrict__ bsum, int nb) {
    int t = threadIdx.x;
    int v = (t < nb) ? bsum[t] : 0;
    int x = v;
    #pragma unroll
    for (int off = 1; off < 64; off <<= 1) { int y = __shfl_up(x, off); if (t >= off) x += y; }
    if (t < nb) bsum[t] = x - v;             // exclusive
}

__global__ __launch_bounds__(1024) void scan_final(const int* __restrict__ deg,
        int* __restrict__ ptr, int* __restrict__ cur, const int* __restrict__ bsum, int N) {
    int i = blockIdx.x * 1024 + threadIdx.x;
    if (i == 0) ptr[0] = 0;
    if (i < N) {
        int p = ptr[i + 1] + bsum[blockIdx.x];
        ptr[i + 1] = p;
        cur[i] = p - deg[i];
    }
}

__global__ void fill_kernel(const int* __restrict__ src, const int* __restrict__ dst,
        int* __restrict__ cur, int* __restrict__ csr, int E) {
    int i = blockIdx.x * 256 + threadIdx.x;
    if (i < E) { int p = atomicAdd(&cur[dst[i]], 1); csr[p] = src[i]; }
}

// ---------------- weight transpose: fp32 W[K][Nn] -> bf16 Wt[Nn][KT] (zero-pad k>=K) ----
__global__ void transpose_w(const float* __restrict__ W, u16* __restrict__ Wt,
        int K, int Nn, int KT) {
    int idx = blockIdx.x * 256 + threadIdx.x;
    if (idx >= Nn * KT) return;
    int n = idx / KT, k = idx - n * KT;
    Wt[(size_t)n * KT + k] = (k < K) ? f2bs(W[(size_t)k * Nn + n]) : (u16)0;
}

// ---------------- x fp32[775] -> bf16[800] padded ----------------
__global__ __launch_bounds__(256) void conv_x(const float* __restrict__ x, u16* __restrict__ xbf) {
    int r = blockIdx.x, t = threadIdx.x;
    const float* row = x + (size_t)r * 775;
    u16* orow = xbf + (size_t)r * 800;
    for (int k = t; k < 800; k += 256)
        orow[k] = (k < 775) ? f2bs(row[k]) : (u16)0;
}

// ---------------- GEMM: C[M,256] fp32 = A[M,K] @ Wt^T (bf16 MFMA) ----------------
template<bool AFP32>
__global__ __launch_bounds__(256) void gemm128(
        const void* __restrict__ Av, int lda, int M, int K,
        const u16* __restrict__ B, int ldb,
        float* __restrict__ C, int ldc) {
    const float* Af = (const float*)Av;
    const u16*   Au = (const u16*)Av;
    __shared__ u16 Alds[128][40];
    __shared__ u16 Blds[128][40];
    const int t = threadIdx.x;
    const int row0 = blockIdx.x * 128, col0 = blockIdx.y * 128;
    const int wid = t >> 6, lane = t & 63;
    const int wm = wid >> 1, wn = wid & 1;
    const int quad = lane >> 4, l16 = lane & 15;

    f32x4 acc[4][4];
    f32x4 z = {0.f, 0.f, 0.f, 0.f};
    #pragma unroll
    for (int i = 0; i < 4; i++)
        #pragma unroll
        for (int j = 0; j < 4; j++) acc[i][j] = z;

    const int kTiles = (K + 31) >> 5;
    for (int kt = 0; kt < kTiles; ++kt) {
        const int k0 = kt << 5;
        #pragma unroll
        for (int c = 0; c < 2; c++) {
            int ch = t + c * 256;
            int r = ch >> 2, cp = (ch & 3) * 8;
            int gr = row0 + r;
            u16x8 v = {0,0,0,0,0,0,0,0};
            if (AFP32) {
                #pragma unroll
                for (int u = 0; u < 8; u++) {
                    int k = k0 + cp + u;
                    v[u] = (gr < M && k < K) ? f2bs(Af[(size_t)gr * lda + k]) : (u16)0;
                }
            } else {
                if (gr < M) v = *(const u16x8*)(Au + (size_t)gr * lda + k0 + cp);
            }
            *(u16x8*)&Alds[r][cp] = v;
        }
        #pragma unroll
        for (int c = 0; c < 2; c++) {
            int ch = t + c * 256;
            int r = ch >> 2, cp = (ch & 3) * 8;
            *(u16x8*)&Blds[r][cp] = *(const u16x8*)(B + (size_t)(col0 + r) * ldb + k0 + cp);
        }
        __syncthreads();
        bf16x8 af[4], bfr[4];
        #pragma unroll
        for (int it = 0; it < 4; it++) af[it] = *(const bf16x8*)&Alds[wm * 64 + it * 16 + l16][quad * 8];
        #pragma unroll
        for (int jt = 0; jt < 4; jt++) bfr[jt] = *(const bf16x8*)&Blds[wn * 64 + jt * 16 + l16][quad * 8];
        #pragma unroll
        for (int it = 0; it < 4; it++)
            #pragma unroll
            for (int jt = 0; jt < 4; jt++)
                acc[it][jt] = __builtin_amdgcn_mfma_f32_16x16x32_bf16(af[it], bfr[jt], acc[it][jt], 0, 0, 0);
        __syncthreads();
    }
    #pragma unroll
    for (int it = 0; it < 4; it++) {
        int gr0 = row0 + wm * 64 + it * 16 + quad * 4;
        #pragma unroll
        for (int jt = 0; jt < 4; jt++) {
            int gc = col0 + wn * 64 + jt * 16 + l16;
            #pragma unroll
            for (int r = 0; r < 4; r++) {
                int gr = gr0 + r;
                if (gr < M) C[(size_t)gr * ldc + gc] = acc[it][jt][r];
            }
        }
    }
}

// GEMM for layer3: C[M,32] fp32 = A[M,256]bf16 @ Wt3^T
__global__ __launch_bounds__(256) void gemm32(
        const u16* __restrict__ A, int lda, int M, int K,
        const u16* __restrict__ B, int ldb, float* __restrict__ C) {
    __shared__ u16 Alds[128][40];
    __shared__ u16 Blds[32][40];
    const int t = threadIdx.x;
    const int row0 = blockIdx.x * 128;
    const int wid = t >> 6, lane = t & 63;
    const int quad = lane >> 4, l16 = lane & 15;
    f32x4 acc[2][2];
    f32x4 z = {0.f, 0.f, 0.f, 0.f};
    acc[0][0] = z; acc[0][1] = z; acc[1][0] = z; acc[1][1] = z;
    const int kTiles = K >> 5;
    for (int kt = 0; kt < kTiles; ++kt) {
        const int k0 = kt << 5;
        #pragma unroll
        for (int c = 0; c < 2; c++) {
            int ch = t + c * 256;
            int r = ch >> 2, cp = (ch & 3) * 8;
            int gr = row0 + r;
            u16x8 v = {0,0,0,0,0,0,0,0};
            if (gr < M) v = *(const u16x8*)(A + (size_t)gr * lda + k0 + cp);
            *(u16x8*)&Alds[r][cp] = v;
        }
        if (t < 128) {
            int r = t >> 2, cp = (t & 3) * 8;
            *(u16x8*)&Blds[r][cp] = *(const u16x8*)(B + (size_t)r * ldb + k0 + cp);
        }
        __syncthreads();
        bf16x8 af[2], bfr[2];
        #pragma unroll
        for (int it = 0; it < 2; it++) af[it] = *(const bf16x8*)&Alds[wid * 32 + it * 16 + l16][quad * 8];
        #pragma unroll
        for (int jt = 0; jt < 2; jt++) bfr[jt] = *(const bf16x8*)&Blds[jt * 16 + l16][quad * 8];
        #pragma unroll
        for (int it = 0; it < 2; it++)
            #pragma unroll
            for (int jt = 0; jt < 2; jt++)
                acc[it][jt] = __builtin_amdgcn_mfma_f32_16x16x32_bf16(af[it], bfr[jt], acc[it][jt], 0, 0, 0);
        __syncthreads();
    }
    #pragma unroll
    for (int it = 0; it < 2; it++) {
        int gr0 = row0 + wid * 32 + it * 16 + quad * 4;
        #pragma unroll
        for (int jt = 0; jt < 2; jt++) {
            int gc = jt * 16 + l16;
            #pragma unroll
            for (int r = 0; r < 4; r++) {
                int gr = gr0 + r;
                if (gr < M) C[(size_t)gr * 32 + gc] = acc[it][jt][r];
            }
        }
    }
}

// ---------------- attention scalars (H=4, C=64) ----------------
__global__ __launch_bounds__(256) void al_kernel(const float* __restrict__ h,
        const float* __restrict__ a_s, const float* __restrict__ a_d,
        float* __restrict__ als, float* __restrict__ ald, int N) {
    int t = threadIdx.x;
    float as = a_s[t], ad = a_d[t];
    int base = blockIdx.x * 8;
    for (int u = 0; u < 8; u++) {
        int n = base + u;
        if (n >= N) return;
        float hv = h[(size_t)n * 256 + t];
        float ps = hv * as, pd = hv * ad;
        for (int off = 32; off >= 1; off >>= 1) { ps += __shfl_down(ps, off); pd += __shfl_down(pd, off); }
        if ((t & 63) == 0) { int w = t >> 6; als[n * 4 + w] = ps; ald[n * 4 + w] = pd; }
    }
}

__global__ __launch_bounds__(256) void al3_kernel(const float* __restrict__ h3,
        const float* __restrict__ a_s, const float* __restrict__ a_d,
        float* __restrict__ als, float* __restrict__ ald, int N) {
    int t = threadIdx.x, wid = t >> 6, lane = t & 63;
    int c = lane & 31, half = lane >> 5;
    float as = a_s[c], ad = a_d[c];
    int n = blockIdx.x * 8 + wid * 2 + half;
    if (n >= N) return;
    float hv = h3[(size_t)n * 32 + c];
    float ps = hv * as, pd = hv * ad;
    for (int off = 16; off >= 1; off >>= 1) { ps += __shfl_down(ps, off, 32); pd += __shfl_down(pd, off, 32); }
    if (c == 0) { als[n] = ps; ald[n] = pd; }
}

// ---------------- softmax-aggregation (H=4, C=64): ONE WAVE PER NODE ----------------
// avg degree ~16 <= 64: single-pass phases, butterfly reductions, alpha via per-wave LDS,
// gather = 64 lanes x float4 = full 256-ch row per edge, src broadcast via shfl.
__global__ __launch_bounds__(256) void agg_kernel(const float* __restrict__ hbuf,
        const float* __restrict__ als, const float* __restrict__ ald,
        const int* __restrict__ ptr, const int* __restrict__ csr,
        const float* __restrict__ bias, u16* __restrict__ act, int N) {
    __shared__ float al_lds[4][64][4];
    const int t = threadIdx.x, wid = t >> 6, lane = t & 63;
    const int i = blockIdx.x * 4 + wid;
    if (i >= N) return;
    const int start = ptr[i], end = ptr[i + 1];
    const int head = lane >> 4;

    const f32x4 aldv = *(const f32x4*)&ald[(size_t)i * 4];
    const f32x4 alsv = *(const f32x4*)&als[(size_t)i * 4];
    f32x4 eself, mx;
    #pragma unroll
    for (int hh = 0; hh < 4; hh++) { eself[hh] = lrelu(alsv[hh] + aldv[hh]); mx[hh] = eself[hh]; }

    // Phase A: max
    for (int j = start + lane; j < end; j += 64) {
        int s = csr[j];
        const f32x4 a = *(const f32x4*)&als[(size_t)s * 4];
        #pragma unroll
        for (int hh = 0; hh < 4; hh++) mx[hh] = fmaxf(mx[hh], lrelu(a[hh] + aldv[hh]));
    }
    #pragma unroll
    for (int off = 32; off >= 1; off >>= 1) {
        #pragma unroll
        for (int hh = 0; hh < 4; hh++) mx[hh] = fmaxf(mx[hh], __shfl_xor(mx[hh], off));
    }
    // Phase B: denom
    f32x4 sm;
    #pragma unroll
    for (int hh = 0; hh < 4; hh++) sm[hh] = (lane == 0) ? expf(eself[hh] - mx[hh]) : 0.f;
    for (int j = start + lane; j < end; j += 64) {
        int s = csr[j];
        const f32x4 a = *(const f32x4*)&als[(size_t)s * 4];
        #pragma unroll
        for (int hh = 0; hh < 4; hh++) sm[hh] += expf(lrelu(a[hh] + aldv[hh]) - mx[hh]);
    }
    #pragma unroll
    for (int off = 32; off >= 1; off >>= 1) {
        #pragma unroll
        for (int hh = 0; hh < 4; hh++) sm[hh] += __shfl_xor(sm[hh], off);
    }
    f32x4 inv;
    #pragma unroll
    for (int hh = 0; hh < 4; hh++) inv[hh] = 1.f / (sm[hh] + 1e-16f);

    // Phase C: gather, self term first
    float aself = expf(eself[head] - mx[head]) * inv[head];
    const f32x4 hvs = *(const f32x4*)&hbuf[(size_t)i * 256 + lane * 4];
    f32x4 acc;
    #pragma unroll
    for (int c2 = 0; c2 < 4; c2++) acc[c2] = aself * hvs[c2];

    for (int base = start; base < end; base += 64) {
        const int n64 = min(64, end - base);
        int sreg = 0;
        const int j = base + lane;
        if (j < end) {
            sreg = csr[j];
            const f32x4 a = *(const f32x4*)&als[(size_t)sreg * 4];
            f32x4 alpha;
            #pragma unroll
            for (int hh = 0; hh < 4; hh++)
                alpha[hh] = expf(lrelu(a[hh] + aldv[hh]) - mx[hh]) * inv[hh];
            *(f32x4*)&al_lds[wid][lane][0] = alpha;
        }
        for (int k = 0; k < n64; ++k) {
            const int s = __shfl(sreg, k);
            const float a = al_lds[wid][k][head];
            const f32x4 hv = *(const f32x4*)&hbuf[(size_t)s * 256 + lane * 4];
            #pragma unroll
            for (int c2 = 0; c2 < 4; c2++) acc[c2] = fmaf(a, hv[c2], acc[c2]);
        }
    }

    const f32x4 bv = *(const f32x4*)&bias[lane * 4];
    u16x4 o;
    #pragma unroll
    for (int c2 = 0; c2 < 4; c2++) o[c2] = f2bs(fmaxf(acc[c2] + bv[c2], 0.f));
    *(u16x4*)&act[(size_t)i * 256 + lane * 4] = o;
}

// ---------------- layer-3 aggregation (H=1, C=32) fused with mean-pool ----------------
__global__ __launch_bounds__(64) void agg3_kernel(const float* __restrict__ h3,
        const float* __restrict__ als, const float* __restrict__ ald,
        const int* __restrict__ ptr, const int* __restrict__ csr,
        float* __restrict__ ews,
        const float* __restrict__ bias, const int* __restrict__ batch,
        float* __restrict__ pool, int* __restrict__ cnt) {
    const int i = blockIdx.x, lane = threadIdx.x;
    const int start = ptr[i], end = ptr[i + 1];
    const float aldv = ald[i];
    float e0 = lrelu(als[i] + aldv);
    float mx = e0;
    for (int j = start + lane; j < end; j += 64) {
        int s = csr[j]; mx = fmaxf(mx, lrelu(als[s] + aldv));
    }
    for (int off = 32; off >= 1; off >>= 1) mx = fmaxf(mx, __shfl_xor(mx, off));
    float m = mx;
    float sm = (lane == 0) ? expf(e0 - m) : 0.f;
    for (int j = start + lane; j < end; j += 64) {
        int s = csr[j];
        float ex = expf(lrelu(als[s] + aldv) - m);
        ews[j] = ex;
        sm += ex;
    }
    for (int off = 32; off >= 1; off >>= 1) sm += __shfl_xor(sm, off);
    float inv = 1.f / (sm + 1e-16f);
    __syncthreads();                                  // drain ews stores
    int c = lane & 31, half = lane >> 5;
    float acc = 0.f;
    for (int j = start + half; j < end; j += 2) {
        int s = csr[j];
        acc = fmaf(ews[j] * inv, h3[(size_t)s * 32 + c], acc);
    }
    acc += __shfl_down(acc, 32);
    if (lane < 32) {
        float val = acc + expf(e0 - m) * inv * h3[(size_t)i * 32 + c] + bias[c];
        int g = batch[i];
        atomicAdd(&pool[g * 32 + c], val);
        if (lane == 0) atomicAdd(&cnt[g], 1);
    }
}

__global__ void final_kernel(const float* __restrict__ pool, const int* __restrict__ cnt,
        float* __restrict__ out) {
    int idx = blockIdx.x * 256 + threadIdx.x;
    int g = idx >> 5;
    out[idx] = pool[idx] / fmaxf((float)cnt[g], 1.f);
}

extern "C" void kernel_launch(void* const* d_in, const int* in_sizes, int n_in,
                              void* d_out, int out_size, void* d_ws, size_t ws_size,
                              hipStream_t stream) {
    const int N = 50000, E = 800000, G = 512;
    const float* x    = (const float*)d_in[0];
    const int*   ei   = (const int*)d_in[1];
    const int*   batch= (const int*)d_in[2];
    const float* W1   = (const float*)d_in[3];
    const float* as1  = (const float*)d_in[4];
    const float* ad1  = (const float*)d_in[5];
    const float* b1   = (const float*)d_in[6];
    const float* W2   = (const float*)d_in[7];
    const float* as2  = (const float*)d_in[8];
    const float* ad2  = (const float*)d_in[9];
    const float* b2   = (const float*)d_in[10];
    const float* W3   = (const float*)d_in[11];
    const float* as3  = (const float*)d_in[12];
    const float* ad3  = (const float*)d_in[13];
    const float* b3   = (const float*)d_in[14];
    const int* esrc = ei;
    const int* edst = ei + E;

    char* base = (char*)d_ws; size_t off = 0;
    auto alloc = [&](size_t bytes) -> void* {
        void* p = base + off; off = (off + bytes + 255) & ~(size_t)255; return p;
    };
    float* hbuf = (float*)alloc((size_t)N * 256 * 4);   // GEMM out / messages (fp32)
    u16*   act  = (u16*)  alloc((size_t)N * 256 * 2);   // bf16 activations
    float* ews  = (float*)alloc((size_t)E * 4);         // per-edge exp workspace (agg3 only)
    float* als  = (float*)alloc((size_t)N * 4 * 4);
    float* ald  = (float*)alloc((size_t)N * 4 * 4);
    int*   deg  = (int*)  alloc((size_t)N * 4);
    int*   ptr  = (int*)  alloc((size_t)(N + 1) * 4);
    int*   cur  = (int*)  alloc((size_t)N * 4);
    int*   csr  = (int*)  alloc((size_t)E * 4);
    u16*   Wt   = (u16*)  alloc((size_t)256 * 800 * 2);
    int*   bsum = (int*)  alloc((size_t)64 * 4);
    float* pool = (float*)alloc((size_t)G * 32 * 4);
    int*   cnt  = (int*)  alloc((size_t)G * 4);
    u16*   xbf  = (u16*)  alloc((size_t)N * 800 * 2);   // optional fast path
    const bool use_xbf = (off <= ws_size);              // deterministic per-run

    hipMemsetAsync(deg, 0, (size_t)N * 4, stream);
    hipMemsetAsync(pool, 0, (size_t)G * 32 * 4, stream);
    hipMemsetAsync(cnt, 0, (size_t)G * 4, stream);

    // CSR over dst (reused by all 3 layers; self-loop handled via eself term)
    const int nb = (N + 1023) / 1024;
    deg_kernel<<<(E + 255) / 256, 256, 0, stream>>>(edst, deg, E);
    scan_local<<<nb, 1024, 0, stream>>>(deg, ptr, bsum, N);
    scan_carry<<<1, 64, 0, stream>>>(bsum, nb);
    scan_final<<<nb, 1024, 0, stream>>>(deg, ptr, cur, bsum, N);
    fill_kernel<<<(E + 255) / 256, 256, 0, stream>>>(esrc, edst, cur, csr, E);

    dim3 g128((N + 127) / 128, 2);
    const int aggGrid = (N + 3) / 4;
    // ---- layer 1 ----
    transpose_w<<<(256 * 800 + 255) / 256, 256, 0, stream>>>(W1, Wt, 775, 256, 800);
    if (use_xbf) {
        conv_x<<<N, 256, 0, stream>>>(x, xbf);
        gemm128<false><<<g128, 256, 0, stream>>>(xbf, 800, N, 775, Wt, 800, hbuf, 256);
    } else {
        gemm128<true><<<g128, 256, 0, stream>>>(x, 775, N, 775, Wt, 800, hbuf, 256);
    }
    al_kernel<<<(N + 7) / 8, 256, 0, stream>>>(hbuf, as1, ad1, als, ald, N);
    agg_kernel<<<aggGrid, 256, 0, stream>>>(hbuf, als, ald, ptr, csr, b1, act, N);
    // ---- layer 2 ----
    transpose_w<<<(256 * 256 + 255) / 256, 256, 0, stream>>>(W2, Wt, 256, 256, 256);
    gemm128<false><<<g128, 256, 0, stream>>>(act, 256, N, 256, Wt, 256, hbuf, 256);
    al_kernel<<<(N + 7) / 8, 256, 0, stream>>>(hbuf, as2, ad2, als, ald, N);
    agg_kernel<<<aggGrid, 256, 0, stream>>>(hbuf, als, ald, ptr, csr, b2, act, N);
    // ---- layer 3 ----
    transpose_w<<<(32 * 256 + 255) / 256, 256, 0, stream>>>(W3, Wt, 256, 32, 256);
    gemm32<<<(N + 127) / 128, 256, 0, stream>>>(act, 256, N, 256, Wt, 256, hbuf);
    al3_kernel<<<(N + 7) / 8, 256, 0, stream>>>(hbuf, as3, ad3, als, ald, N);
    agg3_kernel<<<N, 64, 0, stream>>>(hbuf, als, ald, ptr, csr, ews, b3, batch, pool, cnt);
    final_kernel<<<(G * 32 + 255) / 256, 256, 0, stream>>>(pool, cnt, (float*)d_out);
}

// Round 5
// 796.405 us; speedup vs baseline: 1.6762x; 1.0901x over previous
//
#include <hip/hip_runtime.h>
#include <hip/hip_bf16.h>

typedef unsigned short u16;
typedef __attribute__((ext_vector_type(4))) unsigned short u16x4;
typedef __attribute__((ext_vector_type(8))) unsigned short u16x8;
typedef __attribute__((ext_vector_type(8))) short bf16x8;
typedef __attribute__((ext_vector_type(4))) float f32x4;

__device__ __forceinline__ u16 f2bs(float f) {
    union { float f; unsigned int u; } x; x.f = f;
    unsigned int r = x.u + 0x7FFFu + ((x.u >> 16) & 1u);   // RNE
    return (u16)(r >> 16);
}
__device__ __forceinline__ float bs2f(u16 u) {
    union { unsigned int u; float f; } x; x.u = ((unsigned int)u) << 16; return x.f;
}
__device__ __forceinline__ float lrelu(float e) { return e >= 0.f ? e : 0.2f * e; }

// ---------------- CSR build ----------------
__global__ void deg_kernel(const int* __restrict__ dst, int* __restrict__ deg, int E) {
    int i = blockIdx.x * 256 + threadIdx.x;
    if (i < E) atomicAdd(&deg[dst[i]], 1);
}

// hierarchical scan: local (1024/block) -> carry scan -> fixup
__global__ __launch_bounds__(1024) void scan_local(const int* __restrict__ deg,
        int* __restrict__ ptr, int* __restrict__ bsum, int N) {
    __shared__ int wsum[16];
    const int t = threadIdx.x, i = blockIdx.x * 1024 + t;
    const int lane = t & 63, w = t >> 6;
    int v = (i < N) ? deg[i] : 0;
    int x = v;
    #pragma unroll
    for (int off = 1; off < 64; off <<= 1) { int y = __shfl_up(x, off); if (lane >= off) x += y; }
    if (lane == 63) wsum[w] = x;
    __syncthreads();
    if (w == 0) {
        int s = (lane < 16) ? wsum[lane] : 0;
        #pragma unroll
        for (int off = 1; off < 16; off <<= 1) { int y = __shfl_up(s, off); if (lane >= off) s += y; }
        if (lane < 16) wsum[lane] = s;
    }
    __syncthreads();
    int incl = x + (w > 0 ? wsum[w - 1] : 0);
    if (i < N) ptr[i + 1] = incl;            // local inclusive; fixed by scan_final
    if (t == 0) bsum[blockIdx.x] = wsum[15];
}

__global__ __launch_bounds__(64) void scan_carry(int* __restrict__ bsum, int nb) {
    int t = threadIdx.x;
    int v = (t < nb) ? bsum[t] : 0;
    int x = v;
    #pragma unroll
    for (int off = 1; off < 64; off <<= 1) { int y = __shfl_up(x, off); if (t >= off) x += y; }
    if (t < nb) bsum[t] = x - v;             // exclusive
}

__global__ __launch_bounds__(1024) void scan_final(const int* __restrict__ deg,
        int* __restrict__ ptr, int* __restrict__ cur, const int* __restrict__ bsum, int N) {
    int i = blockIdx.x * 1024 + threadIdx.x;
    if (i == 0) ptr[0] = 0;
    if (i < N) {
        int p = ptr[i + 1] + bsum[blockIdx.x];
        ptr[i + 1] = p;
        cur[i] = p - deg[i];
    }
}

__global__ void fill_kernel(const int* __restrict__ src, const int* __restrict__ dst,
        int* __restrict__ cur, int* __restrict__ csr, int E) {
    int i = blockIdx.x * 256 + threadIdx.x;
    if (i < E) { int p = atomicAdd(&cur[dst[i]], 1); csr[p] = src[i]; }
}

// ---------------- weight transpose: fp32 W[K][Nn] -> bf16 Wt[Nn][KT] (zero-pad k>=K) ----
__global__ void transpose_w(const float* __restrict__ W, u16* __restrict__ Wt,
        int K, int Nn, int KT) {
    int idx = blockIdx.x * 256 + threadIdx.x;
    if (idx >= Nn * KT) return;
    int n = idx / KT, k = idx - n * KT;
    Wt[(size_t)n * KT + k] = (k < K) ? f2bs(W[(size_t)k * Nn + n]) : (u16)0;
}

// ---------------- x fp32[775] -> bf16[800] padded ----------------
__global__ __launch_bounds__(256) void conv_x(const float* __restrict__ x, u16* __restrict__ xbf) {
    int r = blockIdx.x, t = threadIdx.x;
    const float* row = x + (size_t)r * 775;
    u16* orow = xbf + (size_t)r * 800;
    for (int k = t; k < 800; k += 256)
        orow[k] = (k < 775) ? f2bs(row[k]) : (u16)0;
}

// ---------------- GEMM: C[M,256] bf16 = A[M,K] @ Wt^T (bf16 MFMA) ----------------
template<bool AFP32>
__global__ __launch_bounds__(256) void gemm128(
        const void* __restrict__ Av, int lda, int M, int K,
        const u16* __restrict__ B, int ldb,
        u16* __restrict__ C, int ldc) {
    const float* Af = (const float*)Av;
    const u16*   Au = (const u16*)Av;
    __shared__ u16 Alds[128][40];
    __shared__ u16 Blds[128][40];
    const int t = threadIdx.x;
    const int row0 = blockIdx.x * 128, col0 = blockIdx.y * 128;
    const int wid = t >> 6, lane = t & 63;
    const int wm = wid >> 1, wn = wid & 1;
    const int quad = lane >> 4, l16 = lane & 15;

    f32x4 acc[4][4];
    f32x4 z = {0.f, 0.f, 0.f, 0.f};
    #pragma unroll
    for (int i = 0; i < 4; i++)
        #pragma unroll
        for (int j = 0; j < 4; j++) acc[i][j] = z;

    const int kTiles = (K + 31) >> 5;
    for (int kt = 0; kt < kTiles; ++kt) {
        const int k0 = kt << 5;
        #pragma unroll
        for (int c = 0; c < 2; c++) {
            int ch = t + c * 256;
            int r = ch >> 2, cp = (ch & 3) * 8;
            int gr = row0 + r;
            u16x8 v = {0,0,0,0,0,0,0,0};
            if (AFP32) {
                #pragma unroll
                for (int u = 0; u < 8; u++) {
                    int k = k0 + cp + u;
                    v[u] = (gr < M && k < K) ? f2bs(Af[(size_t)gr * lda + k]) : (u16)0;
                }
            } else {
                if (gr < M) v = *(const u16x8*)(Au + (size_t)gr * lda + k0 + cp);
            }
            *(u16x8*)&Alds[r][cp] = v;
        }
        #pragma unroll
        for (int c = 0; c < 2; c++) {
            int ch = t + c * 256;
            int r = ch >> 2, cp = (ch & 3) * 8;
            *(u16x8*)&Blds[r][cp] = *(const u16x8*)(B + (size_t)(col0 + r) * ldb + k0 + cp);
        }
        __syncthreads();
        bf16x8 af[4], bfr[4];
        #pragma unroll
        for (int it = 0; it < 4; it++) af[it] = *(const bf16x8*)&Alds[wm * 64 + it * 16 + l16][quad * 8];
        #pragma unroll
        for (int jt = 0; jt < 4; jt++) bfr[jt] = *(const bf16x8*)&Blds[wn * 64 + jt * 16 + l16][quad * 8];
        #pragma unroll
        for (int it = 0; it < 4; it++)
            #pragma unroll
            for (int jt = 0; jt < 4; jt++)
                acc[it][jt] = __builtin_amdgcn_mfma_f32_16x16x32_bf16(af[it], bfr[jt], acc[it][jt], 0, 0, 0);
        __syncthreads();
    }
    #pragma unroll
    for (int it = 0; it < 4; it++) {
        int gr0 = row0 + wm * 64 + it * 16 + quad * 4;
        #pragma unroll
        for (int jt = 0; jt < 4; jt++) {
            int gc = col0 + wn * 64 + jt * 16 + l16;
            #pragma unroll
            for (int r = 0; r < 4; r++) {
                int gr = gr0 + r;
                if (gr < M) C[(size_t)gr * ldc + gc] = f2bs(acc[it][jt][r]);
            }
        }
    }
}

// GEMM for layer3: C[M,32] fp32 = A[M,256]bf16 @ Wt3^T (h3 stays fp32 — tiny)
__global__ __launch_bounds__(256) void gemm32(
        const u16* __restrict__ A, int lda, int M, int K,
        const u16* __restrict__ B, int ldb, float* __restrict__ C) {
    __shared__ u16 Alds[128][40];
    __shared__ u16 Blds[32][40];
    const int t = threadIdx.x;
    const int row0 = blockIdx.x * 128;
    const int wid = t >> 6, lane = t & 63;
    const int quad = lane >> 4, l16 = lane & 15;
    f32x4 acc[2][2];
    f32x4 z = {0.f, 0.f, 0.f, 0.f};
    acc[0][0] = z; acc[0][1] = z; acc[1][0] = z; acc[1][1] = z;
    const int kTiles = K >> 5;
    for (int kt = 0; kt < kTiles; ++kt) {
        const int k0 = kt << 5;
        #pragma unroll
        for (int c = 0; c < 2; c++) {
            int ch = t + c * 256;
            int r = ch >> 2, cp = (ch & 3) * 8;
            int gr = row0 + r;
            u16x8 v = {0,0,0,0,0,0,0,0};
            if (gr < M) v = *(const u16x8*)(A + (size_t)gr * lda + k0 + cp);
            *(u16x8*)&Alds[r][cp] = v;
        }
        if (t < 128) {
            int r = t >> 2, cp = (t & 3) * 8;
            *(u16x8*)&Blds[r][cp] = *(const u16x8*)(B + (size_t)r * ldb + k0 + cp);
        }
        __syncthreads();
        bf16x8 af[2], bfr[2];
        #pragma unroll
        for (int it = 0; it < 2; it++) af[it] = *(const bf16x8*)&Alds[wid * 32 + it * 16 + l16][quad * 8];
        #pragma unroll
        for (int jt = 0; jt < 2; jt++) bfr[jt] = *(const bf16x8*)&Blds[jt * 16 + l16][quad * 8];
        #pragma unroll
        for (int it = 0; it < 2; it++)
            #pragma unroll
            for (int jt = 0; jt < 2; jt++)
                acc[it][jt] = __builtin_amdgcn_mfma_f32_16x16x32_bf16(af[it], bfr[jt], acc[it][jt], 0, 0, 0);
        __syncthreads();
    }
    #pragma unroll
    for (int it = 0; it < 2; it++) {
        int gr0 = row0 + wid * 32 + it * 16 + quad * 4;
        #pragma unroll
        for (int jt = 0; jt < 2; jt++) {
            int gc = jt * 16 + l16;
            #pragma unroll
            for (int r = 0; r < 4; r++) {
                int gr = gr0 + r;
                if (gr < M) C[(size_t)gr * 32 + gc] = acc[it][jt][r];
            }
        }
    }
}

// ---------------- attention scalars (H=4, C=64), bf16 h ----------------
__global__ __launch_bounds__(256) void al_kernel(const u16* __restrict__ h,
        const float* __restrict__ a_s, const float* __restrict__ a_d,
        float* __restrict__ als, float* __restrict__ ald, int N) {
    int t = threadIdx.x;
    float as = a_s[t], ad = a_d[t];
    int base = blockIdx.x * 8;
    for (int u = 0; u < 8; u++) {
        int n = base + u;
        if (n >= N) return;
        float hv = bs2f(h[(size_t)n * 256 + t]);
        float ps = hv * as, pd = hv * ad;
        for (int off = 32; off >= 1; off >>= 1) { ps += __shfl_down(ps, off); pd += __shfl_down(pd, off); }
        if ((t & 63) == 0) { int w = t >> 6; als[n * 4 + w] = ps; ald[n * 4 + w] = pd; }
    }
}

__global__ __launch_bounds__(256) void al3_kernel(const float* __restrict__ h3,
        const float* __restrict__ a_s, const float* __restrict__ a_d,
        float* __restrict__ als, float* __restrict__ ald, int N) {
    int t = threadIdx.x, wid = t >> 6, lane = t & 63;
    int c = lane & 31, half = lane >> 5;
    float as = a_s[c], ad = a_d[c];
    int n = blockIdx.x * 8 + wid * 2 + half;
    if (n >= N) return;
    float hv = h3[(size_t)n * 32 + c];
    float ps = hv * as, pd = hv * ad;
    for (int off = 16; off >= 1; off >>= 1) { ps += __shfl_down(ps, off, 32); pd += __shfl_down(pd, off, 32); }
    if (c == 0) { als[n] = ps; ald[n] = pd; }
}

// ---------------- softmax-aggregation (H=4, C=64): one wave per node, bf16 h ----------------
__global__ __launch_bounds__(256) void agg_kernel(const u16* __restrict__ hbuf,
        const float* __restrict__ als, const float* __restrict__ ald,
        const int* __restrict__ ptr, const int* __restrict__ csr,
        const float* __restrict__ bias, u16* __restrict__ act, int N) {
    __shared__ float al_lds[4][64][4];
    const int t = threadIdx.x, wid = t >> 6, lane = t & 63;
    const int i = blockIdx.x * 4 + wid;
    if (i >= N) return;
    const int start = ptr[i], end = ptr[i + 1];
    const int head = lane >> 4;

    const f32x4 aldv = *(const f32x4*)&ald[(size_t)i * 4];
    const f32x4 alsv = *(const f32x4*)&als[(size_t)i * 4];
    f32x4 eself, mx;
    #pragma unroll
    for (int hh = 0; hh < 4; hh++) { eself[hh] = lrelu(alsv[hh] + aldv[hh]); mx[hh] = eself[hh]; }

    // Phase A: max
    for (int j = start + lane; j < end; j += 64) {
        int s = csr[j];
        const f32x4 a = *(const f32x4*)&als[(size_t)s * 4];
        #pragma unroll
        for (int hh = 0; hh < 4; hh++) mx[hh] = fmaxf(mx[hh], lrelu(a[hh] + aldv[hh]));
    }
    #pragma unroll
    for (int off = 32; off >= 1; off >>= 1) {
        #pragma unroll
        for (int hh = 0; hh < 4; hh++) mx[hh] = fmaxf(mx[hh], __shfl_xor(mx[hh], off));
    }
    // Phase B: denom
    f32x4 sm;
    #pragma unroll
    for (int hh = 0; hh < 4; hh++) sm[hh] = (lane == 0) ? expf(eself[hh] - mx[hh]) : 0.f;
    for (int j = start + lane; j < end; j += 64) {
        int s = csr[j];
        const f32x4 a = *(const f32x4*)&als[(size_t)s * 4];
        #pragma unroll
        for (int hh = 0; hh < 4; hh++) sm[hh] += expf(lrelu(a[hh] + aldv[hh]) - mx[hh]);
    }
    #pragma unroll
    for (int off = 32; off >= 1; off >>= 1) {
        #pragma unroll
        for (int hh = 0; hh < 4; hh++) sm[hh] += __shfl_xor(sm[hh], off);
    }
    f32x4 inv;
    #pragma unroll
    for (int hh = 0; hh < 4; hh++) inv[hh] = 1.f / (sm[hh] + 1e-16f);

    // Phase C: gather (bf16 rows, 8 B/lane), self term first
    float aself = expf(eself[head] - mx[head]) * inv[head];
    const u16x4 hrs = *(const u16x4*)&hbuf[(size_t)i * 256 + lane * 4];
    f32x4 acc;
    #pragma unroll
    for (int c2 = 0; c2 < 4; c2++) acc[c2] = aself * bs2f(hrs[c2]);

    for (int base = start; base < end; base += 64) {
        const int n64 = min(64, end - base);
        int sreg = 0;
        const int j = base + lane;
        if (j < end) {
            sreg = csr[j];
            const f32x4 a = *(const f32x4*)&als[(size_t)sreg * 4];
            f32x4 alpha;
            #pragma unroll
            for (int hh = 0; hh < 4; hh++)
                alpha[hh] = expf(lrelu(a[hh] + aldv[hh]) - mx[hh]) * inv[hh];
            *(f32x4*)&al_lds[wid][lane][0] = alpha;
        }
        for (int k = 0; k < n64; ++k) {
            const int s = __shfl(sreg, k);
            const float a = al_lds[wid][k][head];
            const u16x4 hr = *(const u16x4*)&hbuf[(size_t)s * 256 + lane * 4];
            #pragma unroll
            for (int c2 = 0; c2 < 4; c2++) acc[c2] = fmaf(a, bs2f(hr[c2]), acc[c2]);
        }
    }

    const f32x4 bv = *(const f32x4*)&bias[lane * 4];
    u16x4 o;
    #pragma unroll
    for (int c2 = 0; c2 < 4; c2++) o[c2] = f2bs(fmaxf(acc[c2] + bv[c2], 0.f));
    *(u16x4*)&act[(size_t)i * 256 + lane * 4] = o;
}

// ---------------- layer-3 aggregation (H=1, C=32): 32 lanes/node, 8 nodes/block ----------
__global__ __launch_bounds__(256) void agg3_kernel(const float* __restrict__ h3,
        const float* __restrict__ als, const float* __restrict__ ald,
        const int* __restrict__ ptr, const int* __restrict__ csr,
        const float* __restrict__ bias, const int* __restrict__ batch,
        float* __restrict__ pool, int* __restrict__ cnt, int N) {
    const int t = threadIdx.x, g32 = t >> 5, lane = t & 31;
    const int i = blockIdx.x * 8 + g32;
    if (i >= N) return;
    const int start = ptr[i], end = ptr[i + 1];
    const float aldv = ald[i];
    const float e0 = lrelu(als[i] + aldv);
    float mx = e0;
    for (int j = start + lane; j < end; j += 32)
        mx = fmaxf(mx, lrelu(als[csr[j]] + aldv));
    #pragma unroll
    for (int off = 16; off >= 1; off >>= 1) mx = fmaxf(mx, __shfl_xor(mx, off, 32));
    float sm = (lane == 0) ? expf(e0 - mx) : 0.f;
    for (int j = start + lane; j < end; j += 32)
        sm += expf(lrelu(als[csr[j]] + aldv) - mx);
    #pragma unroll
    for (int off = 16; off >= 1; off >>= 1) sm += __shfl_xor(sm, off, 32);
    const float inv = 1.f / (sm + 1e-16f);

    float acc = expf(e0 - mx) * inv * h3[(size_t)i * 32 + lane];
    for (int base = start; base < end; base += 32) {
        const int n32 = min(32, end - base);
        int sreg = 0; float areg = 0.f;
        const int j = base + lane;
        if (j < end) {
            sreg = csr[j];
            areg = expf(lrelu(als[sreg] + aldv) - mx) * inv;
        }
        for (int k = 0; k < n32; ++k) {
            const int s = __shfl(sreg, k, 32);
            const float a = __shfl(areg, k, 32);
            acc = fmaf(a, h3[(size_t)s * 32 + lane], acc);
        }
    }
    const float val = acc + bias[lane];          // no ReLU on layer 3
    const int g = batch[i];
    atomicAdd(&pool[g * 32 + lane], val);
    if (lane == 0) atomicAdd(&cnt[g], 1);
}

__global__ void final_kernel(const float* __restrict__ pool, const int* __restrict__ cnt,
        float* __restrict__ out) {
    int idx = blockIdx.x * 256 + threadIdx.x;
    int g = idx >> 5;
    out[idx] = pool[idx] / fmaxf((float)cnt[g], 1.f);
}

extern "C" void kernel_launch(void* const* d_in, const int* in_sizes, int n_in,
                              void* d_out, int out_size, void* d_ws, size_t ws_size,
                              hipStream_t stream) {
    const int N = 50000, E = 800000, G = 512;
    const float* x    = (const float*)d_in[0];
    const int*   ei   = (const int*)d_in[1];
    const int*   batch= (const int*)d_in[2];
    const float* W1   = (const float*)d_in[3];
    const float* as1  = (const float*)d_in[4];
    const float* ad1  = (const float*)d_in[5];
    const float* b1   = (const float*)d_in[6];
    const float* W2   = (const float*)d_in[7];
    const float* as2  = (const float*)d_in[8];
    const float* ad2  = (const float*)d_in[9];
    const float* b2   = (const float*)d_in[10];
    const float* W3   = (const float*)d_in[11];
    const float* as3  = (const float*)d_in[12];
    const float* ad3  = (const float*)d_in[13];
    const float* b3   = (const float*)d_in[14];
    const int* esrc = ei;
    const int* edst = ei + E;

    char* base = (char*)d_ws; size_t off = 0;
    auto alloc = [&](size_t bytes) -> void* {
        void* p = base + off; off = (off + bytes + 255) & ~(size_t)255; return p;
    };
    u16*   hbuf = (u16*)  alloc((size_t)N * 256 * 2);   // GEMM out / messages (bf16)
    u16*   act  = (u16*)  alloc((size_t)N * 256 * 2);   // bf16 activations
    float* h3   = (float*)alloc((size_t)N * 32 * 4);    // layer-3 pre-agg (fp32)
    float* als  = (float*)alloc((size_t)N * 4 * 4);
    float* ald  = (float*)alloc((size_t)N * 4 * 4);
    int*   deg  = (int*)  alloc((size_t)N * 4);
    int*   ptr  = (int*)  alloc((size_t)(N + 1) * 4);
    int*   cur  = (int*)  alloc((size_t)N * 4);
    int*   csr  = (int*)  alloc((size_t)E * 4);
    u16*   Wt   = (u16*)  alloc((size_t)256 * 800 * 2);
    int*   bsum = (int*)  alloc((size_t)64 * 4);
    float* pool = (float*)alloc((size_t)G * 32 * 4);
    int*   cnt  = (int*)  alloc((size_t)G * 4);
    u16*   xbf  = (u16*)  alloc((size_t)N * 800 * 2);   // optional fast path
    const bool use_xbf = (off <= ws_size);              // deterministic per-run

    hipMemsetAsync(deg, 0, (size_t)N * 4, stream);
    hipMemsetAsync(pool, 0, (size_t)G * 32 * 4, stream);
    hipMemsetAsync(cnt, 0, (size_t)G * 4, stream);

    // CSR over dst (reused by all 3 layers; self-loop handled via eself term)
    const int nb = (N + 1023) / 1024;
    deg_kernel<<<(E + 255) / 256, 256, 0, stream>>>(edst, deg, E);
    scan_local<<<nb, 1024, 0, stream>>>(deg, ptr, bsum, N);
    scan_carry<<<1, 64, 0, stream>>>(bsum, nb);
    scan_final<<<nb, 1024, 0, stream>>>(deg, ptr, cur, bsum, N);
    fill_kernel<<<(E + 255) / 256, 256, 0, stream>>>(esrc, edst, cur, csr, E);

    dim3 g128((N + 127) / 128, 2);
    const int aggGrid = (N + 3) / 4;
    // ---- layer 1 ----
    transpose_w<<<(256 * 800 + 255) / 256, 256, 0, stream>>>(W1, Wt, 775, 256, 800);
    if (use_xbf) {
        conv_x<<<N, 256, 0, stream>>>(x, xbf);
        gemm128<false><<<g128, 256, 0, stream>>>(xbf, 800, N, 775, Wt, 800, hbuf, 256);
    } else {
        gemm128<true><<<g128, 256, 0, stream>>>(x, 775, N, 775, Wt, 800, hbuf, 256);
    }
    al_kernel<<<(N + 7) / 8, 256, 0, stream>>>(hbuf, as1, ad1, als, ald, N);
    agg_kernel<<<aggGrid, 256, 0, stream>>>(hbuf, als, ald, ptr, csr, b1, act, N);
    // ---- layer 2 ----
    transpose_w<<<(256 * 256 + 255) / 256, 256, 0, stream>>>(W2, Wt, 256, 256, 256);
    gemm128<false><<<g128, 256, 0, stream>>>(act, 256, N, 256, Wt, 256, hbuf, 256);
    al_kernel<<<(N + 7) / 8, 256, 0, stream>>>(hbuf, as2, ad2, als, ald, N);
    agg_kernel<<<aggGrid, 256, 0, stream>>>(hbuf, als, ald, ptr, csr, b2, act, N);
    // ---- layer 3 ----
    transpose_w<<<(32 * 256 + 255) / 256, 256, 0, stream>>>(W3, Wt, 256, 32, 256);
    gemm32<<<(N + 127) / 128, 256, 0, stream>>>(act, 256, N, 256, Wt, 256, h3);
    al3_kernel<<<(N + 7) / 8, 256, 0, stream>>>(h3, as3, ad3, als, ald, N);
    agg3_kernel<<<(N + 7) / 8, 256, 0, stream>>>(h3, als, ald, ptr, csr, b3, batch, pool, cnt, N);
    final_kernel<<<(G * 32 + 255) / 256, 256, 0, stream>>>(pool, cnt, (float*)d_out);
}